// Round 5
// baseline (208.648 us; speedup 1.0000x reference)
//
#include <hip/hip_runtime.h>
#include <cstdint>
#include <cmath>

#define NN 100000      // nodes
#define NC 8           // communities
#define NF 256         // features (and D)
#define XPARTS_FLOATS ((size_t)NC * NN * NF)   // 204,800,000
#define ROWS 128       // rows per scatter block
#define THR  512       // threads per scatter block

typedef float f32x4 __attribute__((ext_vector_type(4)));

// ---- K1: phi_raw[n][c] = mean(z[n, c*32:(c+1)*32]) in fp64, coalesced -----
__global__ __launch_bounds__(256) void k_phi_raw(const f32x4* __restrict__ z4,
                                                 double* __restrict__ raw) {
    int gid = blockIdx.x * 256 + threadIdx.x;
    int n = gid >> 6;
    int l = gid & 63;
    if (n >= NN) return;
    f32x4 v = z4[(size_t)n * 64 + l];
    double s = ((double)v.x + (double)v.y) + ((double)v.z + (double)v.w);
    s += __shfl_xor(s, 1, 64);
    s += __shfl_xor(s, 2, 64);
    s += __shfl_xor(s, 4, 64);
    if ((l & 7) == 0) raw[(size_t)n * NC + (l >> 3)] = s * (1.0 / 32.0);
}

// ---- K2: per-block column sum-of-exp partials (max-free, fp64) ------------
// raw = mean of 32 N(0,1) -> |raw| < ~0.5, exp never overflows: no max needed.
__global__ __launch_bounds__(256) void k_col_partial(const double* __restrict__ raw,
                                                     double* __restrict__ part) {
    __shared__ double ss[256][NC];
    int tid = threadIdx.x;
    int gtid = blockIdx.x * 256 + tid;
    double s[NC];
#pragma unroll
    for (int c = 0; c < NC; ++c) s[c] = 0.0;
    for (int n = gtid; n < NN; n += 256 * 256) {
        const double* rp = raw + (size_t)n * NC;
#pragma unroll
        for (int c = 0; c < NC; ++c) s[c] += exp(rp[c]);
    }
#pragma unroll
    for (int c = 0; c < NC; ++c) ss[tid][c] = s[c];
    __syncthreads();
    for (int off = 128; off > 0; off >>= 1) {
        if (tid < off) {
#pragma unroll
            for (int c = 0; c < NC; ++c) ss[tid][c] += ss[tid + off][c];
        }
        __syncthreads();
    }
    if (tid == 0) {
#pragma unroll
        for (int c = 0; c < NC; ++c) part[(size_t)blockIdx.x * NC + c] = ss[0][c];
    }
}

// ---- K5f: fused merge + mask + scatter ------------------------------------
// Loads x first (nontemporal, in flight during merge+mask), then branchless
// full-block store path. 128 rows/block, 512 threads, 16 f32x4/thread.
__global__ __launch_bounds__(THR) void k_scatter_fused(
    const f32x4* __restrict__ x4, const double* __restrict__ raw,
    const double* __restrict__ part, float* __restrict__ mask_out,
    f32x4* __restrict__ out4) {
    __shared__ double ss[256][NC];    // 16 KB merge scratch
    __shared__ float mlds[ROWS * NC]; // 4 KB mask
    int tid = threadIdx.x;
    int r0 = blockIdx.x * ROWS;
    int nrows = NN - r0; if (nrows > ROWS) nrows = ROWS;
    bool full = (nrows == ROWS);
    int nvec = nrows * 64;
    size_t base = (size_t)r0 * 64;

    // (1) issue x loads first — HBM reads overlap the merge/mask math below
    f32x4 v[16];
    if (full) {
#pragma unroll
        for (int i = 0; i < 16; ++i)
            v[i] = __builtin_nontemporal_load(&x4[base + i * THR + tid]);
    } else {
#pragma unroll
        for (int i = 0; i < 16; ++i) {
            int idx = i * THR + tid;
            v[i] = (idx < nvec) ? __builtin_nontemporal_load(&x4[base + idx])
                                : (f32x4)(0.f);
        }
    }

    // (2) merge the 256x8 column partials (L2-resident) -> fin in ss[0][*]
    if (tid < 256) {
#pragma unroll
        for (int c = 0; c < NC; ++c) ss[tid][c] = part[(size_t)tid * NC + c];
    }
    __syncthreads();
    for (int off = 128; off > 0; off >>= 1) {
        if (tid < off) {
#pragma unroll
            for (int c = 0; c < NC; ++c) ss[tid][c] += ss[tid + off][c];
        }
        __syncthreads();
    }

    // (3) per-row mask in fp64: threads 0..nrows-1
    if (tid < nrows) {
        int n = r0 + tid;
        double phi[NC];
        double r = 0.0;
#pragma unroll
        for (int c = 0; c < NC; ++c) {
            phi[c] = exp(raw[(size_t)n * NC + c]) / ss[0][c];
            r += phi[c];
        }
        double f = 8.0 - r;   // global sum of rowsums == 8 exactly
        double w[NC];
        double wmax = -1e300;
#pragma unroll
        for (int c = 0; c < NC; ++c) { w[c] = phi[c] * f; wmax = fmax(wmax, w[c]); }
#pragma unroll
        for (int c = 0; c < NC; ++c) {
            float bitf = ((w[c] == wmax) || (w[c] >= 1.0)) ? 1.0f : 0.0f;
            mlds[tid * NC + c] = bitf;
            mask_out[(size_t)n * NC + c] = bitf;
        }
    }
    __syncthreads();

    // (4) scatter: c-major, 128 KB contiguous stream per community
    const f32x4 zz = (f32x4)(0.f);
    if (full) {
#pragma unroll
        for (int c = 0; c < NC; ++c) {
            size_t cbase = (size_t)c * NN * 64 + base;
#pragma unroll
            for (int i = 0; i < 16; ++i) {
                int idx = i * THR + tid;
                int lr = idx >> 6;                      // wave-uniform row
                bool bit = mlds[lr * NC + c] != 0.0f;   // LDS broadcast
                __builtin_nontemporal_store(bit ? v[i] : zz, &out4[cbase + idx]);
            }
        }
    } else {
#pragma unroll
        for (int c = 0; c < NC; ++c) {
            size_t cbase = (size_t)c * NN * 64 + base;
#pragma unroll
            for (int i = 0; i < 16; ++i) {
                int idx = i * THR + tid;
                if (idx < nvec) {
                    int lr = idx >> 6;
                    bool bit = mlds[lr * NC + c] != 0.0f;
                    __builtin_nontemporal_store(bit ? v[i] : zz, &out4[cbase + idx]);
                }
            }
        }
    }
}

// ================= fallback path (scratch inside d_out) ====================
__global__ __launch_bounds__(256) void k_col_final(const double* __restrict__ part,
                                                   double* __restrict__ fin) {
    __shared__ double ss[256][NC];
    int tid = threadIdx.x;
#pragma unroll
    for (int c = 0; c < NC; ++c) ss[tid][c] = part[(size_t)tid * NC + c];
    __syncthreads();
    for (int off = 128; off > 0; off >>= 1) {
        if (tid < off) {
#pragma unroll
            for (int c = 0; c < NC; ++c) ss[tid][c] += ss[tid + off][c];
        }
        __syncthreads();
    }
    if (tid == 0) {
#pragma unroll
        for (int c = 0; c < NC; ++c) fin[c] = ss[0][c];
    }
}

__global__ __launch_bounds__(256) void k_mask(const double* __restrict__ raw,
                                              const double* __restrict__ fin,
                                              float* __restrict__ mask_out) {
    int n = blockIdx.x * blockDim.x + threadIdx.x;
    if (n >= NN) return;
    double phi[NC];
    double r = 0.0;
#pragma unroll
    for (int c = 0; c < NC; ++c) {
        phi[c] = exp(raw[(size_t)n * NC + c]) / fin[c];
        r += phi[c];
    }
    double f = 8.0 - r;
    double w[NC];
    double wmax = -1e300;
#pragma unroll
    for (int c = 0; c < NC; ++c) { w[c] = phi[c] * f; wmax = fmax(wmax, w[c]); }
#pragma unroll
    for (int c = 0; c < NC; ++c) {
        bool bit = (w[c] == wmax) || (w[c] >= 1.0);
        mask_out[(size_t)n * NC + c] = bit ? 1.0f : 0.0f;
    }
}

__global__ __launch_bounds__(256) void k_scatter(const f32x4* __restrict__ x4,
                                                 const float* __restrict__ mask,
                                                 f32x4* __restrict__ out4) {
    __shared__ float mlds[64 * NC];
    int tid = threadIdx.x;
    int r0 = blockIdx.x * 64;
    int nrows = NN - r0; if (nrows > 64) nrows = 64;
    int nvec = nrows * 64;
    size_t base = (size_t)r0 * 64;
    for (int k = tid; k < nrows * NC; k += 256)
        mlds[k] = mask[(size_t)r0 * NC + k];
    f32x4 v[16];
#pragma unroll
    for (int i = 0; i < 16; ++i) {
        int idx = i * 256 + tid;
        v[i] = (idx < nvec) ? x4[base + idx] : (f32x4)(0.f);
    }
    __syncthreads();
    const f32x4 zz = (f32x4)(0.f);
#pragma unroll
    for (int c = 0; c < NC; ++c) {
        size_t cbase = (size_t)c * NN * 64 + base;
#pragma unroll
        for (int i = 0; i < 16; ++i) {
            int idx = i * 256 + tid;
            if (idx < nvec) {
                int lr = idx >> 6;
                bool bit = mlds[lr * NC + c] != 0.0f;
                __builtin_nontemporal_store(bit ? v[i] : zz, &out4[cbase + idx]);
            }
        }
    }
}

extern "C" void kernel_launch(void* const* d_in, const int* in_sizes, int n_in,
                              void* d_out, int out_size, void* d_ws, size_t ws_size,
                              hipStream_t stream) {
    const f32x4* x4 = (const f32x4*)d_in[0];
    const f32x4* z4 = (const f32x4*)d_in[1];
    float* out = (float*)d_out;
    float* mask_out = out + XPARTS_FLOATS;

    const size_t RAW_BYTES  = (size_t)NN * NC * sizeof(double);   // 6.4 MB
    const size_t PART_BYTES = 256 * NC * sizeof(double);          // 16 KB

    if (ws_size >= RAW_BYTES + PART_BYTES) {
        // 3-kernel path: scratch in d_ws, mask fused into scatter
        double* raw  = (double*)d_ws;
        double* part = (double*)((char*)d_ws + RAW_BYTES);
        k_phi_raw      <<<(NN * 64 + 255) / 256, 256, 0, stream>>>(z4, raw);
        k_col_partial  <<<256, 256, 0, stream>>>(raw, part);
        k_scatter_fused<<<(NN + ROWS - 1) / ROWS, THR, 0, stream>>>(x4, raw, part,
                                                                    mask_out, (f32x4*)out);
    } else {
        // 5-kernel fallback: scratch carved from x_parts region of d_out
        double* raw  = (double*)out;
        double* part = (double*)(out + 2000000);
        double* fin  = (double*)(out + 2200000);
        k_phi_raw    <<<(NN * 64 + 255) / 256, 256, 0, stream>>>(z4, raw);
        k_col_partial<<<256, 256, 0, stream>>>(raw, part);
        k_col_final  <<<1, 256, 0, stream>>>(part, fin);
        k_mask       <<<(NN + 255) / 256, 256, 0, stream>>>(raw, fin, mask_out);
        k_scatter    <<<(NN + 63) / 64, 256, 0, stream>>>(x4, mask_out, (f32x4*)out);
    }
}